// Round 1
// baseline (886.737 us; speedup 1.0000x reference)
//
#include <hip/hip_runtime.h>
#include <hip/hip_bf16.h>

#define RR 7
#define EPSBN 1e-5f
#define LDA 136   // 128 + 8 bf16 pad
#define LDW 136

typedef __attribute__((ext_vector_type(8))) __bf16 bf16x8;
typedef __attribute__((ext_vector_type(4))) float f32x4;

__device__ __forceinline__ float b2f(unsigned short u) {
    union { unsigned int i; float f; } c; c.i = ((unsigned int)u) << 16; return c.f;
}
__device__ __forceinline__ unsigned short f2b(float f) {
    union { float f; unsigned int i; } c; c.f = f;
    unsigned int x = c.i;
    return (unsigned short)((x + 0x7fffu + ((x >> 16) & 1u)) >> 16);
}

// ---------------- CSR build ----------------
__global__ void zero_i32_k(int* p, int n) {
    int i = blockIdx.x * 256 + threadIdx.x; if (i < n) p[i] = 0;
}
__global__ void copy_i32_k(const int* __restrict__ a, int* __restrict__ b, int n) {
    int i = blockIdx.x * 256 + threadIdx.x; if (i < n) b[i] = a[i];
}
__global__ void hist_k(const int* __restrict__ dst, const int* __restrict__ et,
                       int* __restrict__ cnt, int ne) {
    int e = blockIdx.x * 256 + threadIdx.x;
    if (e < ne) atomicAdd(&cnt[dst[e] * RR + et[e]], 1);
}
__global__ void scan1_k(const int* __restrict__ cnt, int* __restrict__ bsum, int n) {
    __shared__ int sh[256];
    int base = blockIdx.x << 10;
    int s = 0;
    for (int i = threadIdx.x; i < 1024; i += 256) { int idx = base + i; if (idx < n) s += cnt[idx]; }
    sh[threadIdx.x] = s; __syncthreads();
    for (int off = 128; off > 0; off >>= 1) {
        if (threadIdx.x < off) sh[threadIdx.x] += sh[threadIdx.x + off];
        __syncthreads();
    }
    if (threadIdx.x == 0) bsum[blockIdx.x] = sh[0];
}
__global__ void scan2_k(int* __restrict__ bsum, int nb) {   // nb <= 1024
    __shared__ int sh[256];
    int t = threadIdx.x;
    int v[4]; int loc = 0;
#pragma unroll
    for (int i = 0; i < 4; ++i) { int idx = t * 4 + i; v[i] = (idx < nb) ? bsum[idx] : 0; loc += v[i]; }
    sh[t] = loc; __syncthreads();
    for (int off = 1; off < 256; off <<= 1) {
        int x = (t >= off) ? sh[t - off] : 0;
        __syncthreads();
        sh[t] += x;
        __syncthreads();
    }
    int ex = (t > 0) ? sh[t - 1] : 0;
#pragma unroll
    for (int i = 0; i < 4; ++i) { int idx = t * 4 + i; if (idx < nb) { int vv = v[i]; bsum[idx] = ex; ex += vv; } }
}
__global__ void scan3_k(const int* __restrict__ cnt, const int* __restrict__ boff,
                        int* __restrict__ ptr, int n, int total) {
    __shared__ int sh[256];
    int t = threadIdx.x;
    int base = (blockIdx.x << 10) + (t << 2);
    int v[4]; int loc = 0;
#pragma unroll
    for (int i = 0; i < 4; ++i) { int idx = base + i; v[i] = (idx < n) ? cnt[idx] : 0; loc += v[i]; }
    sh[t] = loc; __syncthreads();
    for (int off = 1; off < 256; off <<= 1) {
        int x = (t >= off) ? sh[t - off] : 0;
        __syncthreads();
        sh[t] += x;
        __syncthreads();
    }
    int ex = boff[blockIdx.x] + ((t > 0) ? sh[t - 1] : 0);
#pragma unroll
    for (int i = 0; i < 4; ++i) { int idx = base + i; if (idx < n) { ptr[idx] = ex; ex += v[i]; } }
    if (blockIdx.x == 0 && t == 0) ptr[n] = total;
}
__global__ void scatter_k(const int* __restrict__ src, const int* __restrict__ dst,
                          const int* __restrict__ et, int* __restrict__ cursor,
                          int* __restrict__ ssorted, int ne) {
    int e = blockIdx.x * 256 + threadIdx.x;
    if (e < ne) {
        int seg = dst[e] * RR + et[e];
        int pos = atomicAdd(&cursor[seg], 1);
        ssorted[pos] = src[e];
    }
}
__global__ void invcnt_k(const int* __restrict__ ptr, float* __restrict__ inv, int n) {
    int i = blockIdx.x * 256 + threadIdx.x;
    if (i < n) { int c = ptr[i + 1] - ptr[i]; inv[i] = 1.f / (float)(c > 0 ? c : 1); }
}

// ---------------- weight / feature prep ----------------
// wall layout: [l][kb][o][i] bf16, kb 0..6 = rel_w[l][kb] transposed, kb 7 = root_w[l] transposed
__global__ void prep_w_k(const float* __restrict__ rel_w, const float* __restrict__ root_w,
                         unsigned short* __restrict__ wall) {
    int idx = blockIdx.x * 256 + threadIdx.x;
    if (idx >= 3 * 8 * 16384) return;
    int l = idx >> 17;          // / (8*16384)
    int r2 = idx & 131071;
    int kb = r2 >> 14;
    int mo = r2 & 16383;
    int o = mo >> 7;
    int i = mo & 127;
    float v = (kb < RR) ? rel_w[(((l * RR + kb) << 7) + i) * 128 + o]
                        : root_w[((l << 7) + i) * 128 + o];
    wall[idx] = f2b(v);
}
__global__ void prep_h_k(const int* __restrict__ x, const float* __restrict__ embed,
                         unsigned short* __restrict__ h, int n) {
    int i = blockIdx.x * 256 + threadIdx.x;
    if (i >= n * 128) return;
    int node = i >> 7, j = i & 127;
    h[i] = f2b(embed[((size_t)x[node] << 7) + j]);
}

// ---------------- fused RGCN layer: CSR mean-aggregate -> MFMA transform ----------------
__global__ __launch_bounds__(256) void layer_k(
    const unsigned short* __restrict__ h_in,   // bf16 [N][128]
    unsigned short* __restrict__ h_out,        // bf16 [N][128]
    const unsigned short* __restrict__ w8,     // bf16 [8][128][128], [kb][o][i]
    const float* __restrict__ bias,            // [128]
    const float* __restrict__ bn_g, const float* __restrict__ bn_b,
    const float* __restrict__ bn_m, const float* __restrict__ bn_v,
    const int* __restrict__ seg_ptr, const int* __restrict__ src_sorted,
    const float* __restrict__ invc,
    int nnodes, int bnrelu)
{
    __shared__ __attribute__((aligned(16))) unsigned short At[64 * LDA];
    __shared__ __attribute__((aligned(16))) unsigned short Wt[128 * LDW];

    const int tid  = threadIdx.x;
    const int wave = tid >> 6;
    const int lane = tid & 63;
    const int lane15 = lane & 15;
    const int quad = lane >> 4;
    const int node0 = blockIdx.x << 6;

    const int a_node = tid >> 2;   // 0..63: node row this thread helps aggregate
    const int a_q = tid & 3;       // 32-col quarter
    const int my_node = node0 + a_node;

    f32x4 acc[8];
#pragma unroll
    for (int i = 0; i < 8; ++i) acc[i] = (f32x4){0.f, 0.f, 0.f, 0.f};

    for (int kb = 0; kb < 8; ++kb) {
        // stage W_kb (already [o][i] in global, coalesced 16B copies)
        const unsigned short* wsrc = w8 + (kb << 14);
#pragma unroll
        for (int c = tid; c < 2048; c += 256) {
            int row = c >> 4;
            int col8 = (c & 15) << 3;
            *(uint4*)&Wt[row * LDW + col8] = *(const uint4*)&wsrc[(row << 7) + col8];
        }
        // build A tile: mean over CSR segment (kb<7) or h itself (root, kb==7)
        float av[32];
#pragma unroll
        for (int i = 0; i < 32; ++i) av[i] = 0.f;
        float scale = 1.f;
        if (my_node < nnodes) {
            int e0, e1;
            if (kb < RR) {
                int seg = my_node * RR + kb;
                e0 = seg_ptr[seg]; e1 = seg_ptr[seg + 1];
                scale = invc[seg];
            } else { e0 = 0; e1 = 1; }
            for (int e = e0; e < e1; ++e) {
                int s = (kb < RR) ? src_sorted[e] : my_node;
                const unsigned short* hp = h_in + ((size_t)s << 7) + (a_q << 5);
#pragma unroll
                for (int c4 = 0; c4 < 4; ++c4) {
                    uint4 v = *(const uint4*)(hp + (c4 << 3));
                    av[c4*8+0] += b2f((unsigned short)(v.x & 0xffffu));
                    av[c4*8+1] += b2f((unsigned short)(v.x >> 16));
                    av[c4*8+2] += b2f((unsigned short)(v.y & 0xffffu));
                    av[c4*8+3] += b2f((unsigned short)(v.y >> 16));
                    av[c4*8+4] += b2f((unsigned short)(v.z & 0xffffu));
                    av[c4*8+5] += b2f((unsigned short)(v.z >> 16));
                    av[c4*8+6] += b2f((unsigned short)(v.w & 0xffffu));
                    av[c4*8+7] += b2f((unsigned short)(v.w >> 16));
                }
            }
        }
#pragma unroll
        for (int c4 = 0; c4 < 4; ++c4) {
            uint4 o4;
            o4.x = (unsigned)f2b(av[c4*8+0]*scale) | ((unsigned)f2b(av[c4*8+1]*scale) << 16);
            o4.y = (unsigned)f2b(av[c4*8+2]*scale) | ((unsigned)f2b(av[c4*8+3]*scale) << 16);
            o4.z = (unsigned)f2b(av[c4*8+4]*scale) | ((unsigned)f2b(av[c4*8+5]*scale) << 16);
            o4.w = (unsigned)f2b(av[c4*8+6]*scale) | ((unsigned)f2b(av[c4*8+7]*scale) << 16);
            *(uint4*)&At[a_node * LDA + (a_q << 5) + (c4 << 3)] = o4;
        }
        __syncthreads();
        // MFMA: wave handles M-tile rows [wave*16, wave*16+16), all 8 N-tiles
        const int arow = (wave << 4) + lane15;
#pragma unroll
        for (int ks = 0; ks < 4; ++ks) {
            bf16x8 af = *(const bf16x8*)&At[arow * LDA + (ks << 5) + (quad << 3)];
#pragma unroll
            for (int nt = 0; nt < 8; ++nt) {
                bf16x8 bfr = *(const bf16x8*)&Wt[((nt << 4) + lane15) * LDW + (ks << 5) + (quad << 3)];
                acc[nt] = __builtin_amdgcn_mfma_f32_16x16x32_bf16(af, bfr, acc[nt], 0, 0, 0);
            }
        }
        __syncthreads();
    }
    // epilogue: +bias, BN, ReLU (layers 0/1), store bf16
    // C/D layout: col = lane&15, row = (lane>>4)*4 + reg  [verified m89/m91]
#pragma unroll
    for (int nt = 0; nt < 8; ++nt) {
        int j = (nt << 4) + lane15;
        float bj = bias[j];
        float sc = 1.f, sh = 0.f;
        if (bnrelu) {
            sc = bn_g[j] * rsqrtf(bn_v[j] + EPSBN);
            sh = bn_b[j] - bn_m[j] * sc;
        }
#pragma unroll
        for (int r = 0; r < 4; ++r) {
            int node = node0 + (wave << 4) + (quad << 2) + r;
            if (node < nnodes) {
                float v = acc[nt][r] + bj;
                if (bnrelu) v = fmaxf(v * sc + sh, 0.f);
                h_out[((size_t)node << 7) + j] = f2b(v);
            }
        }
    }
}

// ---------------- MLP head: 16 rows/block, fully in-LDS ----------------
__global__ __launch_bounds__(256) void mlp_k(
    const unsigned short* __restrict__ hfin,
    const int* __restrict__ home, const int* __restrict__ away,
    const float* __restrict__ w0, const float* __restrict__ bb0,
    const float* __restrict__ w1, const float* __restrict__ bb1,
    const float* __restrict__ w2, const float* __restrict__ bb2,
    float* __restrict__ out, int Bn)
{
    __shared__ __attribute__((aligned(16))) float g0[16][256];
    __shared__ __attribute__((aligned(16))) float g1[16][256];
    __shared__ float lg[16][4];
    int t = threadIdx.x;
    {
        int row = t >> 4;
        int cseg = (t & 15) << 4;
        int gr = (blockIdx.x << 4) + row;
        int gc = (gr < Bn) ? gr : 0;
        int hn = home[gc], an = away[gc];
        const unsigned short* sp = (cseg < 128) ? (hfin + ((size_t)hn << 7) + cseg)
                                                : (hfin + ((size_t)an << 7) + (cseg - 128));
#pragma unroll
        for (int c8 = 0; c8 < 2; ++c8) {
            uint4 v = *(const uint4*)(sp + (c8 << 3));
            int base = cseg + (c8 << 3);
            g0[row][base+0] = b2f((unsigned short)(v.x & 0xffffu));
            g0[row][base+1] = b2f((unsigned short)(v.x >> 16));
            g0[row][base+2] = b2f((unsigned short)(v.y & 0xffffu));
            g0[row][base+3] = b2f((unsigned short)(v.y >> 16));
            g0[row][base+4] = b2f((unsigned short)(v.z & 0xffffu));
            g0[row][base+5] = b2f((unsigned short)(v.z >> 16));
            g0[row][base+6] = b2f((unsigned short)(v.w & 0xffffu));
            g0[row][base+7] = b2f((unsigned short)(v.w >> 16));
        }
    }
    __syncthreads();
    {   // fc0: thread t = output col, 16 rows each
        float acc[16];
#pragma unroll
        for (int r = 0; r < 16; ++r) acc[r] = 0.f;
        const float* wr = w0 + (t << 8);
        for (int i = 0; i < 256; i += 4) {
            float4 w = *(const float4*)(wr + i);
#pragma unroll
            for (int r = 0; r < 16; ++r) {
                float4 g = *(const float4*)&g0[r][i];
                acc[r] += w.x * g.x + w.y * g.y + w.z * g.z + w.w * g.w;
            }
        }
        float bb = bb0[t];
#pragma unroll
        for (int r = 0; r < 16; ++r) g1[r][t] = fmaxf(acc[r] + bb, 0.f);
    }
    __syncthreads();
    {   // fc1: 128 outs x 2 row-groups; writes g2 into g0[..][0..127]
        int o = t & 127, rg = t >> 7;
        float acc[8];
#pragma unroll
        for (int r = 0; r < 8; ++r) acc[r] = 0.f;
        const float* wr = w1 + (o << 8);
        for (int i = 0; i < 256; i += 4) {
            float4 w = *(const float4*)(wr + i);
#pragma unroll
            for (int r = 0; r < 8; ++r) {
                float4 g = *(const float4*)&g1[(rg << 3) + r][i];
                acc[r] += w.x * g.x + w.y * g.y + w.z * g.z + w.w * g.w;
            }
        }
        float bb = bb1[o];
#pragma unroll
        for (int r = 0; r < 8; ++r) g0[(rg << 3) + r][o] = fmaxf(acc[r] + bb, 0.f);
    }
    __syncthreads();
    if (t < 48) {   // fc2
        int row = t / 3, cls = t - row * 3;
        const float* wr = w2 + (cls << 7);
        float a = 0.f;
        for (int i = 0; i < 128; i += 4) {
            float4 w = *(const float4*)(wr + i);
            float4 g = *(const float4*)&g0[row][i];
            a += w.x * g.x + w.y * g.y + w.z * g.z + w.w * g.w;
        }
        lg[row][cls] = a + bb2[cls];
    }
    __syncthreads();
    if (t < 16) {   // log_softmax + store
        int gr = (blockIdx.x << 4) + t;
        if (gr < Bn) {
            float l0 = lg[t][0], l1 = lg[t][1], l2 = lg[t][2];
            float m = fmaxf(l0, fmaxf(l1, l2));
            float lse = m + logf(expf(l0 - m) + expf(l1 - m) + expf(l2 - m));
            out[gr * 3 + 0] = l0 - lse;
            out[gr * 3 + 1] = l1 - lse;
            out[gr * 3 + 2] = l2 - lse;
        }
    }
}

extern "C" void kernel_launch(void* const* d_in, const int* in_sizes, int n_in,
                              void* d_out, int out_size, void* d_ws, size_t ws_size,
                              hipStream_t stream) {
    const int*   x      = (const int*)d_in[0];
    const int*   eidx   = (const int*)d_in[1];   // [2, E]
    const int*   etype  = (const int*)d_in[2];
    const int*   home   = (const int*)d_in[3];
    const int*   away   = (const int*)d_in[4];
    const float* embed  = (const float*)d_in[5];
    const float* rel_w  = (const float*)d_in[6];
    const float* root_w = (const float*)d_in[7];
    const float* conv_b = (const float*)d_in[8];
    const float* bn_g   = (const float*)d_in[9];
    const float* bn_b   = (const float*)d_in[10];
    const float* bn_m   = (const float*)d_in[11];
    const float* bn_v   = (const float*)d_in[12];
    const float* fc0w   = (const float*)d_in[13];
    const float* fc0b   = (const float*)d_in[14];
    const float* fc1w   = (const float*)d_in[15];
    const float* fc1b   = (const float*)d_in[16];
    const float* fc2w   = (const float*)d_in[17];
    const float* fc2b   = (const float*)d_in[18];
    float* out = (float*)d_out;

    const int N_ = in_sizes[0];
    const int E_ = in_sizes[2];
    const int B_ = in_sizes[3];
    const int NS = N_ * RR;

    char* ws = (char*)d_ws;
    auto alloc = [&](size_t bytes) -> char* {
        char* p = ws;
        ws += (bytes + 255) & ~(size_t)255;
        return p;
    };
    int* ptr         = (int*)alloc((size_t)(NS + 1) * 4);
    int* cursor      = (int*)alloc((size_t)NS * 4);
    int* bsum        = (int*)alloc(4096);
    int* src_sorted  = (int*)alloc((size_t)E_ * 4);
    float* invc      = (float*)alloc((size_t)NS * 4);
    unsigned short* wall = (unsigned short*)alloc((size_t)3 * 8 * 16384 * 2);
    unsigned short* hA   = (unsigned short*)alloc((size_t)N_ * 128 * 2);
    unsigned short* hB   = (unsigned short*)alloc((size_t)N_ * 128 * 2);

    const int nb = (NS + 1023) / 1024;

    // CSR build (segments constant across layers)
    zero_i32_k<<<(NS + 255) / 256, 256, 0, stream>>>(cursor, NS);
    hist_k<<<(E_ + 255) / 256, 256, 0, stream>>>(eidx + E_, etype, cursor, E_);
    scan1_k<<<nb, 256, 0, stream>>>(cursor, bsum, NS);
    scan2_k<<<1, 256, 0, stream>>>(bsum, nb);
    scan3_k<<<nb, 256, 0, stream>>>(cursor, bsum, ptr, NS, E_);
    invcnt_k<<<(NS + 255) / 256, 256, 0, stream>>>(ptr, invc, NS);
    copy_i32_k<<<(NS + 255) / 256, 256, 0, stream>>>(ptr, cursor, NS);
    scatter_k<<<(E_ + 255) / 256, 256, 0, stream>>>(eidx, eidx + E_, etype, cursor, src_sorted, E_);

    // weight + feature prep
    prep_w_k<<<(3 * 8 * 16384 + 255) / 256, 256, 0, stream>>>(rel_w, root_w, wall);
    prep_h_k<<<(N_ * 128 + 255) / 256, 256, 0, stream>>>(x, embed, hA, N_);

    const int lgrid = (N_ + 63) / 64;
    layer_k<<<lgrid, 256, 0, stream>>>(hA, hB, wall + 0 * 8 * 16384, conv_b + 0,
                                       bn_g + 0, bn_b + 0, bn_m + 0, bn_v + 0,
                                       ptr, src_sorted, invc, N_, 1);
    layer_k<<<lgrid, 256, 0, stream>>>(hB, hA, wall + 1 * 8 * 16384, conv_b + 128,
                                       bn_g + 128, bn_b + 128, bn_m + 128, bn_v + 128,
                                       ptr, src_sorted, invc, N_, 1);
    layer_k<<<lgrid, 256, 0, stream>>>(hA, hB, wall + 2 * 8 * 16384, conv_b + 256,
                                       bn_g, bn_b, bn_m, bn_v,
                                       ptr, src_sorted, invc, N_, 0);

    mlp_k<<<(B_ + 15) / 16, 256, 0, stream>>>(hB, home, away, fc0w, fc0b, fc1w, fc1b,
                                              fc2w, fc2b, out, B_);
}